// Round 1
// baseline (1468.167 us; speedup 1.0000x reference)
//
#include <hip/hip_runtime.h>

#define TT 2048
#define FF 12
#define CH 128
#define L2E 1.44269504088896340736f

typedef float v2f __attribute__((ext_vector_type(2)));

__device__ __forceinline__ float fast_exp2(float x){ return __builtin_amdgcn_exp2f(x); }
__device__ __forceinline__ float fast_rcp(float x){ return __builtin_amdgcn_rcpf(x); }
__device__ __forceinline__ v2f fma2(v2f a, v2f b, v2f c){ return __builtin_elementwise_fma(a, b, c); }
__device__ __forceinline__ v2f mk2(float x, float y){ v2f r; r.x = x; r.y = y; return r; }

// One block per batch element (256 blocks = 256 CUs), 384 threads = 6 waves.
// Lane mapping: gate q = tid&3 (0=i,1=f,2=g,3=o), unit u = tid>>2, row g = q*96+u.
// Each lane holds W_hh[g][0:96) as 48 float2 (pk-fma) and W_ih[g][0:21) in VGPRs.
// Per step: ONE barrier. h is double-buffered in LDS and read as wave-uniform
// broadcast float4 (conflict-free). Gate combine is 3 intra-4-lane shuffles;
// the q==0 lane owns c,h. The x-part (W_ih·x + b) for step r+1 is computed in
// the pre-barrier slack (depends only on the staged chunk, not on h).
__global__ __launch_bounds__(384, 2) void lstm_persist(
  const float* __restrict__ seq, const int* __restrict__ ev, const int* __restrict__ rsi,
  const int* __restrict__ len, const float* __restrict__ eemb, const float* __restrict__ remb,
  const float* __restrict__ W_ih, const float* __restrict__ W_hh,
  const float* __restrict__ b_ih, const float* __restrict__ b_hh,
  const float* __restrict__ W_mlp, const float* __restrict__ b_mlp,
  const float* __restrict__ W_fc, const float* __restrict__ b_fc,
  float* __restrict__ out)
{
  const int b   = blockIdx.x;
  const int tid = threadIdx.x;
  const int qg  = tid & 3;     // 0=i 1=f 2=g 3=o
  const int u   = tid >> 2;    // hidden unit 0..95
  const int g   = qg*96 + u;   // gate row

  __shared__ __align__(16) float xf[CH*24];     // [r][0..11]=seq, [12..20]=emb, pad to 24
  __shared__ __align__(16) float vhbuf[2*96];   // double-buffered h
  __shared__ __align__(16) float lastk[3*96];
  __shared__ __align__(16) float et[192];
  __shared__ __align__(16) float rt[24];
  __shared__ __align__(16) float accs[192];
  __shared__ __align__(16) float h2[2*96];
  __shared__ int evb[CH];
  __shared__ int rsb[CH];

  // ---- prologue: per-lane weight rows into registers ----
  v2f wh[48];
  {
    const float4* wp = (const float4*)(W_hh + g*96);
    #pragma unroll
    for (int k = 0; k < 24; ++k) {
      const float4 q4 = wp[k];
      wh[2*k]   = mk2(q4.x, q4.y);
      wh[2*k+1] = mk2(q4.z, q4.w);
    }
  }
  float wi[21];
  #pragma unroll
  for (int c = 0; c < 21; ++c) wi[c] = W_ih[g*21 + c];
  const float bg = b_ih[g] + b_hh[g];

  if (tid < 192) { vhbuf[tid] = 0.f; et[tid] = eemb[tid]; }
  if (tid < 24)  rt[tid] = remb[tid];
  if (tid < 288) lastk[tid] = 0.f;

  float c_state = 0.f;
  const int L = len[b];   // state frozen past L; outputs past L unused

  for (int t0 = 0; t0 < L; t0 += CH) {
    // ---- stage: coalesced seq chunk + indices ----
    #pragma unroll
    for (int qq = 0; qq < 4; ++qq) {
      const int i = tid + qq*384;                 // 0..1535 = CH*12
      const int r = i/12, c = i - r*12;
      xf[r*24 + c] = seq[(size_t)b*(TT*FF) + (size_t)t0*FF + i];
    }
    if (tid < CH) {
      evb[tid] = ev [b*TT + t0 + tid];
      rsb[tid] = rsi[b*TT + t0 + tid];
    }
    __syncthreads();
    // ---- embedding gather into cols 12..23 ----
    #pragma unroll
    for (int qq = 0; qq < 4; ++qq) {
      const int i = tid + qq*384;
      const int r = i/12, cc = i - r*12 + 12;
      float v;
      if (cc < 18)      v = et[evb[r]*6 + (cc-12)];
      else if (cc < 21) v = rt[rsb[r]*3 + (cc-18)];
      else              v = 0.f;
      xf[r*24 + cc] = v;
    }
    __syncthreads();

    const int nr = min(CH, L - t0);
    // x-part (incl. bias) for step 0
    float xp;
    {
      const float* xr = xf;
      float s0 = bg, s1 = 0.f, s2 = 0.f;
      #pragma unroll
      for (int c = 0; c < 7; ++c) {
        s0 = fmaf(wi[c],    xr[c],    s0);
        s1 = fmaf(wi[c+7],  xr[c+7],  s1);
        s2 = fmaf(wi[c+14], xr[c+14], s2);
      }
      xp = s0 + s1 + s2;
    }

    for (int r = 0; r < nr; ++r) {
      // ---- h-dot: broadcast reads of h (parity buffer r&1) ----
      const float4* hq = (const float4*)(vhbuf + (r&1)*96);
      v2f a0 = mk2(xp, 0.f), a1 = mk2(0.f,0.f), a2 = mk2(0.f,0.f), a3 = mk2(0.f,0.f);
      #pragma unroll
      for (int k = 0; k < 24; k += 2) {
        const float4 h4 = hq[k];
        const float4 h5 = hq[k+1];
        a0 = fma2(wh[2*k],   mk2(h4.x,h4.y), a0);
        a1 = fma2(wh[2*k+1], mk2(h4.z,h4.w), a1);
        a2 = fma2(wh[2*k+2], mk2(h5.x,h5.y), a2);
        a3 = fma2(wh[2*k+3], mk2(h5.z,h5.w), a3);
      }
      const float s = ((a0.x+a0.y)+(a1.x+a1.y)) + ((a2.x+a2.y)+(a3.x+a3.y));
      // ---- activation in-lane ----
      const bool is_t = (qg == 2);
      const float arg = is_t ? (-2.f*L2E)*fabsf(s) : (-L2E)*s;
      const float e  = fast_exp2(arg);
      const float r1 = fast_rcp(1.f + e);
      const float th = copysignf((1.f - e)*r1, s);
      const float a  = is_t ? th : r1;
      // ---- gate combine: 3 intra-4-lane shuffles ----
      const float t1 = __shfl_xor(a, 2);    // q0 gets g; q1 gets o
      const float t2 = __shfl_xor(a, 1);    // q0 gets f
      const float t3 = __shfl_xor(t1, 1);   // q0 gets o
      if (qg == 0) {
        c_state = fmaf(t2, c_state, a*t1);              // f*c + i*g
        const float e2  = fast_exp2((-2.f*L2E)*fabsf(c_state));
        const float th2 = copysignf((1.f - e2)*fast_rcp(1.f + e2), c_state);
        const float hn  = t3 * th2;                     // o * tanh(c)
        vhbuf[((r&1)^1)*96 + u] = hn;
        const int kk = (t0 + r) + 3 - L;                // last-K ring, t in [L-3,L)
        if (kk >= 0) lastk[kk*96 + u] = hn;
      }
      // ---- pre-barrier slack: x-part for step r+1 (independent of h) ----
      if (r + 1 < nr) {
        const float* xr = xf + (r+1)*24;
        float s0 = bg, s1 = 0.f, s2 = 0.f;
        #pragma unroll
        for (int c = 0; c < 7; ++c) {
          s0 = fmaf(wi[c],    xr[c],    s0);
          s1 = fmaf(wi[c+7],  xr[c+7],  s1);
          s2 = fmaf(wi[c+14], xr[c+14], s2);
        }
        xp = s0 + s1 + s2;
      }
      __syncthreads();
    }
  }

  // ---- epilogue: h_fin in buffer L&1; h_lastk = relu(W_mlp@lastk+b); out = W_fc@[h_fin|h_lastk]+b ----
  const float* hf = vhbuf + (L & 1)*96;
  if (tid < 192) {
    const int half = tid / 96;
    const int m    = tid - half*96;
    const float* wp = W_mlp + m*288 + half*144;
    const float* xq = lastk + half*144;
    float s = 0.f;
    #pragma unroll 8
    for (int i = 0; i < 144; ++i) s = fmaf(wp[i], xq[i], s);
    accs[tid] = s;
  }
  __syncthreads();
  if (tid < 96) {
    const float hl = accs[tid] + accs[96+tid] + b_mlp[tid];
    h2[96 + tid] = fmaxf(hl, 0.f);
    h2[tid] = hf[tid];
  }
  __syncthreads();
  if (tid < 128) {
    const int o  = tid >> 6;
    const int ll = tid & 63;
    const float* wf = W_fc + o*192 + 3*ll;
    float s = fmaf(wf[0], h2[3*ll+0], fmaf(wf[1], h2[3*ll+1], wf[2]*h2[3*ll+2]));
    #pragma unroll
    for (int off = 32; off > 0; off >>= 1) s += __shfl_down(s, off);
    if (ll == 0) out[b*2 + o] = s + b_fc[o];
  }
}

extern "C" void kernel_launch(void* const* d_in, const int* in_sizes, int n_in,
                              void* d_out, int out_size, void* d_ws, size_t ws_size,
                              hipStream_t stream) {
  const float* seq   = (const float*)d_in[0];
  const int*   ev    = (const int*)  d_in[1];
  const int*   rsi   = (const int*)  d_in[2];
  const int*   len   = (const int*)  d_in[3];
  const float* eemb  = (const float*)d_in[4];
  const float* remb  = (const float*)d_in[5];
  const float* W_ih  = (const float*)d_in[6];
  const float* W_hh  = (const float*)d_in[7];
  const float* b_ih  = (const float*)d_in[8];
  const float* b_hh  = (const float*)d_in[9];
  const float* W_mlp = (const float*)d_in[10];
  const float* b_mlp = (const float*)d_in[11];
  const float* W_fc  = (const float*)d_in[12];
  const float* b_fc  = (const float*)d_in[13];

  hipLaunchKernelGGL(lstm_persist, dim3(256), dim3(384), 0, stream,
                     seq, ev, rsi, len, eemb, remb, W_ih, W_hh, b_ih, b_hh,
                     W_mlp, b_mlp, W_fc, b_fc, (float*)d_out);
}